// Round 4
// baseline (129.668 us; speedup 1.0000x reference)
//
#include <hip/hip_runtime.h>
#include <math.h>

#define BLOCK 256
#define NN 100
#define CN 25     // boxes per chunk, 4 chunks
#define NPAD 28   // tile row stride (floats); 28*4B=112B, 16B-aligned rows

__device__ __forceinline__ float fast_rcp(float x) { return __builtin_amdgcn_rcpf(x); }

// ---------------------------------------------------------------------------
// Kernel 1: zero the packed per-box (iou, ~anchor) atomic accumulators.
// ---------------------------------------------------------------------------
__global__ void __launch_bounds__(BLOCK) bbp_init(unsigned long long* __restrict__ packed, int n) {
    int i = blockIdx.x * BLOCK + threadIdx.x;
    if (i < n) packed[i] = 0ull;
}

// ---------------------------------------------------------------------------
// Kernel 2: per-anchor IoU rows + transposed per-box block reduction.
//  - boxes read via wave-uniform global loads (s_load path, scalar cache)
//  - tile layout [anchor][NPAD], b128 writes, 25-box chunks (28.7 KB)
//  - phase 2: 200 threads = 25 boxes x 8 segments x 32 anchors, rotated scan
//    (<=2-way bank aliasing = free), exact first-argmax tie-break,
//    packed-u64 combine, 1 atomicMax per (block, box).
// ---------------------------------------------------------------------------
__global__ void __launch_bounds__(BLOCK, 5) bbp_match(
    const float* __restrict__ anchors,            // [A,4] cbox (cx,cy,w,h)
    const float* __restrict__ bboxes,             // [B,N,4] bbox
    float* __restrict__ max_iou_anchor,           // [B,A]
    int* __restrict__ box_indice,                 // [B,A]
    int* __restrict__ winner,                     // [B,A] -> -1
    unsigned long long* __restrict__ packed,      // [B,N]
    int A, int N) {
    const int b = blockIdx.y;
    const int tid = threadIdx.x;
    const int a = blockIdx.x * BLOCK + tid;
    const int blockbase = blockIdx.x * BLOCK;

    __shared__ float tile[BLOCK * NPAD];               // 28672 B
    __shared__ unsigned long long spart[CN * 9];       // 1800 B

    const int aa = (a < A) ? a : (A - 1);
    const float4 ac = *(const float4*)(anchors + (size_t)aa * 4);
    const float ax1 = ac.x - ac.z * 0.5f;
    const float ay1 = ac.y - ac.w * 0.5f;
    const float ax2 = ac.x + ac.z * 0.5f;
    const float ay2 = ac.y + ac.w * 0.5f;
    const float area_a = (ax2 - ax1) * (ay2 - ay1);

    const float* bbase = bboxes + (size_t)b * NN * 4;  // wave-uniform base
    float* row = &tile[tid * NPAD];

    float best = -1.0f;
    int bi = 0;

    for (int c = 0; c < 4; ++c) {
        const int n0 = c * CN;
        // ---- phase 1: 25 IoUs, b128 tile writes ----
        float4 vbuf;
        #pragma unroll
        for (int k = 0; k < CN; ++k) {
            const int n = n0 + k;
            const float4 bb = *(const float4*)(bbase + 4 * n);   // uniform -> s_load
            const float sa = (bb.z - bb.x) * (bb.w - bb.y);
            float lx = fmaxf(ax1, bb.x), ly = fmaxf(ay1, bb.y);
            float rx = fminf(ax2, bb.z), ry = fminf(ay2, bb.w);
            float w = fmaxf(rx - lx, 0.0f), h = fmaxf(ry - ly, 0.0f);
            float inter = w * h;
            float iou = inter * fast_rcp(area_a + sa - inter);
            if (iou > best) { best = iou; bi = n; }   // strict > : first argmax
            if (k == CN - 1) {
                row[CN - 1] = iou;                     // tail single store
            } else {
                ((float*)&vbuf)[k & 3] = iou;
                if ((k & 3) == 3) *(float4*)(row + (k & ~3)) = vbuf;
            }
        }
        __syncthreads();
        // ---- phase 2: rotated column scan, (box n, segment s) per thread ----
        if (tid < CN * 8) {
            const int n = tid >> 3;
            const int s = tid & 7;
            float bm = -1.0f; int bgi = 0x7FFFFFFF;
            #pragma unroll
            for (int j = 0; j < 32; ++j) {
                const int e = (j + s) & 31;
                const int gi = s * 32 + e;
                float v = tile[gi * NPAD + n];
                if (v > bm || (v == bm && gi < bgi)) { bm = v; bgi = gi; }
            }
            unsigned anch = (unsigned)(blockbase + bgi);
            spart[n * 9 + s] = ((unsigned long long)__float_as_uint(bm) << 32)
                             | (unsigned long long)(0xFFFFFFFFu - anch);
        }
        __syncthreads();
        if (tid < CN) {
            unsigned long long m = spart[tid * 9];
            #pragma unroll
            for (int j = 1; j < 8; ++j) {
                unsigned long long o = spart[tid * 9 + j];
                if (o > m) m = o;
            }
            atomicMax(&packed[(size_t)b * N + n0 + tid], m);
        }
        // no trailing barrier: next chunk's tile writes are fenced by the
        // post-phase-1 barrier; spart reuse fenced by the same barrier.
    }

    if (a < A) {
        const size_t idx = (size_t)b * A + a;
        max_iou_anchor[idx] = best;
        box_indice[idx] = bi;
        winner[idx] = -1;
    }
}

// ---------------------------------------------------------------------------
// Kernel 3: segment_max(tgt_ids, anchor_indice) -> winner via atomicMax.
// ---------------------------------------------------------------------------
__global__ void __launch_bounds__(BLOCK) bbp_scatter(
    const unsigned long long* __restrict__ packed, int* __restrict__ winner,
    int A, int N, int B) {
    int i = blockIdx.x * BLOCK + threadIdx.x;
    if (i >= B * N) return;
    int b = i / N;
    int n = i - b * N;
    unsigned an = 0xFFFFFFFFu - (unsigned)(packed[i] & 0xFFFFFFFFull);
    if (an < (unsigned)A)
        atomicMax(&winner[(size_t)b * A + an], n);
}

// ---------------------------------------------------------------------------
// Kernel 4: apply override, score, one-hot conf, delta encoding.
// ---------------------------------------------------------------------------
__global__ void __launch_bounds__(BLOCK) bbp_finalize(
    const float* __restrict__ anchors, const float* __restrict__ bboxes,
    const int* __restrict__ labels, const float* __restrict__ mean4,
    const float* __restrict__ std4, const float* __restrict__ thr_p,
    const float* __restrict__ max_iou_anchor, const int* __restrict__ box_indice,
    const int* __restrict__ winner, const unsigned long long* __restrict__ packed,
    float* __restrict__ out_conf, float* __restrict__ out_deltas,
    int A, int N, int C) {
    const int b = blockIdx.y;
    const int a = blockIdx.x * BLOCK + threadIdx.x;
    if (a >= A) return;
    const float thr = thr_p[0];
    const size_t idx = (size_t)b * A + a;

    int w = winner[idx];
    bool valid = (w >= 0);
    int bi = valid ? w : box_indice[idx];
    float miou = valid ? __uint_as_float((unsigned)(packed[(size_t)b * N + w] >> 32))
                       : max_iou_anchor[idx];
    float mb = __uint_as_float((unsigned)(packed[(size_t)b * N + bi] >> 32));
    float denom = fmaxf(mb, thr);
    if (miou < thr * 0.5f) miou = 0.0f;
    float score = miou * fast_rcp(denom);
    int lab = labels[(size_t)b * N + bi];
    if (lab <= 0) { score = 0.0f; lab = 0; }

    for (int c = 0; c < C; ++c)
        out_conf[idx * C + c] = (lab == c + 1) ? score : 0.0f;

    float4 bb = *(const float4*)(bboxes + ((size_t)b * N + bi) * 4);
    float4 ac = *(const float4*)(anchors + (size_t)a * 4);
    float cx = (bb.x + bb.z) * 0.5f;
    float cy = (bb.y + bb.w) * 0.5f;
    float bw = bb.z - bb.x;
    float bh = bb.w - bb.y;
    const float rz = fast_rcp(ac.z), rw = fast_rcp(ac.w);
    float4 d;
    d.x = ((cx - ac.x) * rz - mean4[0]) * fast_rcp(std4[0]);
    d.y = ((cy - ac.y) * rw - mean4[1]) * fast_rcp(std4[1]);
    d.z = (__logf(bw * rz) - mean4[2]) * fast_rcp(std4[2]);
    d.w = (__logf(bh * rw) - mean4[3]) * fast_rcp(std4[3]);
    *(float4*)(out_deltas + idx * 4) = d;
}

// ---------------------------------------------------------------------------
extern "C" void kernel_launch(void* const* d_in, const int* in_sizes, int n_in,
                              void* d_out, int out_size, void* d_ws, size_t ws_size,
                              hipStream_t stream) {
    const float* anchors = (const float*)d_in[0];
    const int* labels = (const int*)d_in[1];
    const float* bboxes = (const float*)d_in[2];
    const float* mean4 = (const float*)d_in[3];
    const float* std4 = (const float*)d_in[4];
    const float* thr_p = (const float*)d_in[5];

    const int A = in_sizes[0] / 4;        // 65536
    const int BN = in_sizes[1];           // 800
    const int N = NN;                     // 100
    const int B = BN / N;                 // 8
    const int C = out_size / (B * A) - 4; // 1

    char* ws = (char*)d_ws;
    unsigned long long* packed = (unsigned long long*)ws;                      // [B*N]
    size_t off = ((size_t)B * N * sizeof(unsigned long long) + 255) & ~(size_t)255;
    float* max_iou_anchor = (float*)(ws + off); off += (size_t)B * A * sizeof(float);
    off = (off + 255) & ~(size_t)255;
    int* box_indice = (int*)(ws + off); off += (size_t)B * A * sizeof(int);
    off = (off + 255) & ~(size_t)255;
    int* winner = (int*)(ws + off);

    float* out_conf = (float*)d_out;
    float* out_deltas = out_conf + (size_t)B * A * C;

    bbp_init<<<dim3((B * N + BLOCK - 1) / BLOCK), dim3(BLOCK), 0, stream>>>(packed, B * N);

    dim3 grid((A + BLOCK - 1) / BLOCK, B);
    bbp_match<<<grid, dim3(BLOCK), 0, stream>>>(anchors, bboxes, max_iou_anchor,
                                                box_indice, winner, packed, A, N);

    bbp_scatter<<<dim3((B * N + BLOCK - 1) / BLOCK), dim3(BLOCK), 0, stream>>>(
        packed, winner, A, N, B);

    bbp_finalize<<<grid, dim3(BLOCK), 0, stream>>>(anchors, bboxes, labels, mean4, std4,
                                                   thr_p, max_iou_anchor, box_indice,
                                                   winner, packed, out_conf, out_deltas,
                                                   A, N, C);
}